// Round 14
// baseline (253.382 us; speedup 1.0000x reference)
//
#include <hip/hip_runtime.h>
#include <math.h>

// ---------------------------------------------------------------------------
// GraphVAE forward. History:
// R1: atomic-convoy -> grid-stride partials. R2: decode thread-per-edge.
// R3: bf16 + unroll + fused z/KL. R4: bucketed CSR build.
// R5: z -> fp8 (L2-resident). R6: tables -> fp8 (FETCH halved, dur flat).
// R7: pre-scaled rows (dinv gather gone) + quarter-wave => 242us.
// R8-R11: planar-split aggregation FAILED (305us). R12: linearity fusion
//     FAILED (264us) - cost is gather LATENCY, not stream bytes.
// R13: R7 revert + decode ILP pipeline => 248us; profile exposed:
//     gemm_k128 49us @ 17% occupancy (65KB LDS -> 2 blocks/CU), and
//     bucket_scatter 49us @ 1.5% VALU (391-way global-atomic contention
//     on bucket cursors).
// R14: (a) gemm_k128 K-chunked (4x32): LDS 65KB -> 17.4KB -> occupancy
//     VGPR-limited ~62%; (b) SCH 4096 -> 16384: 98 blocks -> 4x less
//     cursor contention, fatter per-bucket write runs.
// ---------------------------------------------------------------------------

#define NRED 2048        // partial-reduction blocks for decode
#define NPB 128          // nodes per bucket (power of 2)
#define NPB_SHIFT 7
#define SCH 16384        // edges per scatter block

typedef float f32x2 __attribute__((ext_vector_type(2)));

#define NTL(p) __builtin_nontemporal_load(&(p))

// dot of 4 fp8 pairs packed in two uints (HW fp8->f32 converts)
__device__ __forceinline__ float dotfp8(unsigned int a, unsigned int b) {
    f32x2 al = __builtin_amdgcn_cvt_pk_f32_fp8(a, false);
    f32x2 ah = __builtin_amdgcn_cvt_pk_f32_fp8(a, true);
    f32x2 bl = __builtin_amdgcn_cvt_pk_f32_fp8(b, false);
    f32x2 bh = __builtin_amdgcn_cvt_pk_f32_fp8(b, true);
    return al.x * bl.x + al.y * bl.y + ah.x * bh.x + ah.y * bh.y;
}

// ---- bucketed CSR build ----------------------------------------------------

__global__ __launch_bounds__(256) void bucket_hist(const int* __restrict__ dst,
        int* __restrict__ bcnt, int E, int nbuck) {
    extern __shared__ int sh[];
    for (int i = threadIdx.x; i < nbuck; i += 256) sh[i] = 0;
    __syncthreads();
    for (int e = blockIdx.x * blockDim.x + threadIdx.x; e < E; e += gridDim.x * blockDim.x)
        atomicAdd(&sh[dst[e] >> NPB_SHIFT], 1);
    __syncthreads();
    for (int i = threadIdx.x; i < nbuck; i += 256)
        if (sh[i]) atomicAdd(&bcnt[i], sh[i]);
}

__global__ __launch_bounds__(1024) void bucket_scan(const int* __restrict__ bcnt,
        int* __restrict__ boff, int* __restrict__ bcur, int E, int nbuck) {
    __shared__ int s[1024];
    int tid = threadIdx.x;
    int v = (tid < nbuck) ? bcnt[tid] : 0;
    s[tid] = v;
    __syncthreads();
    for (int off = 1; off < 1024; off <<= 1) {
        int t = (tid >= off) ? s[tid - off] : 0;
        __syncthreads();
        if (tid >= off) s[tid] += t;
        __syncthreads();
    }
    if (tid < nbuck) {
        int excl = s[tid] - v;
        boff[tid] = excl;
        bcur[tid] = excl;
    }
    if (tid == 0) boff[nbuck] = E;
}

// Scatter packed (src<<7 | dst&127) into bucket regions.
__global__ __launch_bounds__(256) void bucket_scatter(const int* __restrict__ ei,
        int* __restrict__ bcur, int* __restrict__ pairs, int E, int nbuck) {
    extern __shared__ int sh[];
    int* hist = sh;
    int* base = sh + nbuck;
    int e0 = blockIdx.x * SCH;
    int e1 = min(e0 + SCH, E);
    for (int i = threadIdx.x; i < nbuck; i += 256) hist[i] = 0;
    __syncthreads();
    for (int e = e0 + threadIdx.x; e < e1; e += 256)
        atomicAdd(&hist[ei[E + e] >> NPB_SHIFT], 1);
    __syncthreads();
    for (int i = threadIdx.x; i < nbuck; i += 256) {
        int c = hist[i];
        base[i] = c ? atomicAdd(&bcur[i], c) : 0;
        hist[i] = 0;
    }
    __syncthreads();
    for (int e = e0 + threadIdx.x; e < e1; e += 256) {
        int s = ei[e], t = ei[E + e];
        int b = t >> NPB_SHIFT;
        int slot = base[b] + atomicAdd(&hist[b], 1);
        pairs[slot] = (s << NPB_SHIFT) | (t & (NPB - 1));
    }
}

__global__ __launch_bounds__(256) void bucket_finalize(const int* __restrict__ pairs,
        const int* __restrict__ boff, int* __restrict__ row_start,
        int* __restrict__ deg, float* __restrict__ dinv, int* __restrict__ col,
        int N, int nbuck) {
    __shared__ int cnt[NPB], start[NPB], cur[NPB];
    int b = blockIdx.x;
    int node0 = b << NPB_SHIFT;
    int p0 = boff[b], p1 = boff[b + 1];
    if (threadIdx.x < NPB) cnt[threadIdx.x] = 0;
    __syncthreads();
    for (int p = p0 + threadIdx.x; p < p1; p += 256)
        atomicAdd(&cnt[pairs[p] & (NPB - 1)], 1);
    __syncthreads();
    if (threadIdx.x == 0) {
        int acc = 0;
        for (int i = 0; i < NPB; ++i) { start[i] = acc; acc += cnt[i]; }
    }
    __syncthreads();
    if (threadIdx.x < NPB) {
        int node = node0 + threadIdx.x;
        if (node < N) {
            int d = cnt[threadIdx.x];
            deg[node] = d;
            row_start[node] = p0 + start[threadIdx.x];
            dinv[node] = rsqrtf((float)(d + 1));
        }
        cur[threadIdx.x] = 0;
    }
    __syncthreads();
    for (int p = p0 + threadIdx.x; p < p1; p += 256) {
        int pr = pairs[p];
        int l = pr & (NPB - 1);
        int slot = p0 + start[l] + atomicAdd(&cur[l], 1);
        col[slot] = pr >> NPB_SHIFT;
    }
}

// ---- dense layers ----------------------------------------------------------

// C[N,64](fp8) = (A[N,128] @ W[128,64]) * dinv[row]  (pre-scaled rows).
// K chunked 4x32: LDS 17.4KB (was 65KB -> 17% occupancy).
__global__ __launch_bounds__(256) void gemm_k128(const float* __restrict__ A,
        const float* __restrict__ W, const float* __restrict__ dinv,
        unsigned int* __restrict__ Cb32, int N) {
    const int K = 128, KC = 32;
    __shared__ float sA[64][KC + 4];   // 9216B
    __shared__ float sW[KC][64];       // 8192B
    int row0 = blockIdx.x * 64;
    int tid = threadIdx.x;
    int ty = tid >> 4, tx = tid & 15;
    int r0 = ty * 4, c0 = tx * 4;
    float4 acc0 = make_float4(0,0,0,0), acc1 = acc0, acc2 = acc0, acc3 = acc0;
    for (int kc = 0; kc < K; kc += KC) {
        __syncthreads();   // previous chunk's compute done before overwrite
        for (int i = tid; i < KC * 64 / 4; i += 256)
            ((float4*)sW)[i] = ((const float4*)(W + (size_t)kc * 64))[i];
        for (int i = tid; i < 64 * KC / 4; i += 256) {
            int r = (i * 4) / KC, c = (i * 4) % KC;
            float4 v = make_float4(0.f, 0.f, 0.f, 0.f);
            if (row0 + r < N) v = *(const float4*)&A[(size_t)(row0 + r) * K + kc + c];
            *(float4*)&sA[r][c] = v;
        }
        __syncthreads();
        for (int k = 0; k < KC; ++k) {
            float4 wv = *(float4*)&sW[k][c0];
            float a0 = sA[r0 + 0][k];
            float a1 = sA[r0 + 1][k];
            float a2 = sA[r0 + 2][k];
            float a3 = sA[r0 + 3][k];
            acc0.x += a0 * wv.x; acc0.y += a0 * wv.y; acc0.z += a0 * wv.z; acc0.w += a0 * wv.w;
            acc1.x += a1 * wv.x; acc1.y += a1 * wv.y; acc1.z += a1 * wv.z; acc1.w += a1 * wv.w;
            acc2.x += a2 * wv.x; acc2.y += a2 * wv.y; acc2.z += a2 * wv.z; acc2.w += a2 * wv.w;
            acc3.x += a3 * wv.x; acc3.y += a3 * wv.y; acc3.z += a3 * wv.z; acc3.w += a3 * wv.w;
        }
    }
    #define ST_F8(i, accv) \
        if (row0 + r0 + i < N) { \
            float di = dinv[row0 + r0 + i]; \
            unsigned int pk = 0; \
            pk = __builtin_amdgcn_cvt_pk_fp8_f32(accv.x * di, accv.y * di, pk, false); \
            pk = __builtin_amdgcn_cvt_pk_fp8_f32(accv.z * di, accv.w * di, pk, true); \
            Cb32[((row0 + r0 + i) << 4) + (c0 >> 2)] = pk; }
    ST_F8(0, acc0) ST_F8(1, acc1) ST_F8(2, acc2) ST_F8(3, acc3)
    #undef ST_F8
}

// ---- aggregations (pull over CSR, pre-scaled fp8 tables) --------------------
// Quarter-wave (16 lanes) per node; lane owns 4 features via one u32 gather.
// Tables pre-scaled by the source row's dinv: out_raw = di*(self + sum row[s]).

#define ACC4(gg, P) { \
    f32x2 L_ = __builtin_amdgcn_cvt_pk_f32_fp8(gg, false); \
    f32x2 H_ = __builtin_amdgcn_cvt_pk_f32_fp8(gg, true); \
    P##0 += L_.x; P##1 += L_.y; P##2 += H_.x; P##3 += H_.y; }

#define AGG_SUM(tab) \
    float a0, a1, a2, a3, b0 = 0.f, b1 = 0.f, b2 = 0.f, b3 = 0.f; \
    { unsigned int v = tab[(q << 4) | l]; \
      f32x2 L_ = __builtin_amdgcn_cvt_pk_f32_fp8(v, false); \
      f32x2 H_ = __builtin_amdgcn_cvt_pk_f32_fp8(v, true); \
      a0 = L_.x; a1 = L_.y; a2 = H_.x; a3 = H_.y; } \
    { int base = row_start[q], d = deg[q]; \
      int j = 0; \
      for (; j + 8 <= d; j += 8) { \
        int s0 = col[base + j + 0], s1 = col[base + j + 1]; \
        int s2 = col[base + j + 2], s3 = col[base + j + 3]; \
        int s4 = col[base + j + 4], s5 = col[base + j + 5]; \
        int s6 = col[base + j + 6], s7 = col[base + j + 7]; \
        unsigned int g0 = tab[(s0 << 4) | l], g1 = tab[(s1 << 4) | l]; \
        unsigned int g2 = tab[(s2 << 4) | l], g3 = tab[(s3 << 4) | l]; \
        unsigned int g4 = tab[(s4 << 4) | l], g5 = tab[(s5 << 4) | l]; \
        unsigned int g6 = tab[(s6 << 4) | l], g7 = tab[(s7 << 4) | l]; \
        ACC4(g0, a) ACC4(g1, b) ACC4(g2, a) ACC4(g3, b) \
        ACC4(g4, a) ACC4(g5, b) ACC4(g6, a) ACC4(g7, b) \
      } \
      for (; j < d; ++j) { \
        int s = col[base + j]; \
        unsigned int g = tab[(s << 4) | l]; \
        ACC4(g, a) \
      } }

// fp8 in -> fp8 out: h = relu(di*sum + b); stored h*di (pre-scaled for next).
__global__ __launch_bounds__(256) void aggregate_q88(const unsigned int* __restrict__ hs,
        unsigned int* __restrict__ hout, const int* __restrict__ row_start,
        const int* __restrict__ deg, const int* __restrict__ col,
        const float* __restrict__ dinv, const float* __restrict__ bias, int N) {
    int q = (blockIdx.x * blockDim.x + threadIdx.x) >> 4;
    int l = threadIdx.x & 15;
    if (q >= N) return;
    float di = dinv[q];
    AGG_SUM(hs)
    float4 bv = *(const float4*)&bias[l << 2];
    float r0 = fmaxf(di * (a0 + b0) + bv.x, 0.f) * di;
    float r1 = fmaxf(di * (a1 + b1) + bv.y, 0.f) * di;
    float r2 = fmaxf(di * (a2 + b2) + bv.z, 0.f) * di;
    float r3 = fmaxf(di * (a3 + b3) + bv.w, 0.f) * di;
    unsigned int pk = 0;
    pk = __builtin_amdgcn_cvt_pk_fp8_f32(r0, r1, pk, false);
    pk = __builtin_amdgcn_cvt_pk_fp8_f32(r2, r3, pk, true);
    hout[(q << 4) | l] = pk;
}

// fp8 in -> f32 out (g = Ahat h), no bias/relu, no output pre-scale.
__global__ __launch_bounds__(256) void aggregate_q8f(const unsigned int* __restrict__ hs,
        float* __restrict__ gout, const int* __restrict__ row_start,
        const int* __restrict__ deg, const int* __restrict__ col,
        const float* __restrict__ dinv, int N) {
    int q = (blockIdx.x * blockDim.x + threadIdx.x) >> 4;
    int l = threadIdx.x & 15;
    if (q >= N) return;
    float di = dinv[q];
    AGG_SUM(hs)
    float4 r;
    r.x = di * (a0 + b0); r.y = di * (a1 + b1);
    r.z = di * (a2 + b2); r.w = di * (a3 + b3);
    *(float4*)&gout[(q << 6) | (l << 2)] = r;
}

// ---- mu/lv GEMM with fused z (fp8) + KL ------------------------------------

__global__ __launch_bounds__(256) void gemm_cat_fused(const float* __restrict__ A,
        const float* __restrict__ Wmu, const float* __restrict__ Wlv,
        const float* __restrict__ bmu, const float* __restrict__ blv,
        const float* __restrict__ eps, unsigned char* __restrict__ zb,
        float* __restrict__ partial_kl, int N) {
    const int K = 64;
    __shared__ float sA[64 * (K + 4)];
    __shared__ float sW[K * 64];
    __shared__ float sB[64];
    int row0 = blockIdx.x * 64;
    int tid = threadIdx.x;
    for (int i = tid; i < K * 64 / 4; i += 256) {
        int k = (i * 4) / 64, c = (i * 4) % 64;
        float4 v;
        if (c < 32) v = *(const float4*)&Wmu[k * 32 + c];
        else        v = *(const float4*)&Wlv[k * 32 + (c - 32)];
        *(float4*)&sW[k * 64 + c] = v;
    }
    if (tid < 32) sB[tid] = bmu[tid];
    else if (tid < 64) sB[tid] = blv[tid - 32];
    for (int i = tid; i < 64 * K / 4; i += 256) {
        int r = (i * 4) / K, c = (i * 4) % K;
        float4 v = make_float4(0.f, 0.f, 0.f, 0.f);
        if (row0 + r < N) v = *(const float4*)&A[(size_t)(row0 + r) * K + c];
        *(float4*)&sA[r * (K + 4) + c] = v;
    }
    __syncthreads();
    int ty = tid >> 4, tx = tid & 15;
    int r0 = ty * 4, c0 = tx * 4;
    float4 acc0 = make_float4(0,0,0,0), acc1 = acc0, acc2 = acc0, acc3 = acc0;
    for (int k = 0; k < K; ++k) {
        float4 wv = *(float4*)&sW[k * 64 + c0];
        float a0 = sA[(r0 + 0) * (K + 4) + k];
        float a1 = sA[(r0 + 1) * (K + 4) + k];
        float a2 = sA[(r0 + 2) * (K + 4) + k];
        float a3 = sA[(r0 + 3) * (K + 4) + k];
        acc0.x += a0 * wv.x; acc0.y += a0 * wv.y; acc0.z += a0 * wv.z; acc0.w += a0 * wv.w;
        acc1.x += a1 * wv.x; acc1.y += a1 * wv.y; acc1.z += a1 * wv.z; acc1.w += a1 * wv.w;
        acc2.x += a2 * wv.x; acc2.y += a2 * wv.y; acc2.z += a2 * wv.z; acc2.w += a2 * wv.w;
        acc3.x += a3 * wv.x; acc3.y += a3 * wv.y; acc3.z += a3 * wv.z; acc3.w += a3 * wv.w;
    }
    float4 bv = *(float4*)&sB[c0];
    acc0.x += bv.x; acc0.y += bv.y; acc0.z += bv.z; acc0.w += bv.w;
    acc1.x += bv.x; acc1.y += bv.y; acc1.z += bv.z; acc1.w += bv.w;
    acc2.x += bv.x; acc2.y += bv.y; acc2.z += bv.z; acc2.w += bv.w;
    acc3.x += bv.x; acc3.y += bv.y; acc3.z += bv.z; acc3.w += bv.w;

    float* sLV = sA;                 // aliased; sA dead after sync
    __syncthreads();
    float t = 0.f;
    if (c0 >= 32) {
        int cc = c0 - 32;
        #define LV(i, accv) { \
            int row = row0 + r0 + i; \
            sLV[(r0 + i) * 33 + cc + 0] = accv.x; \
            sLV[(r0 + i) * 33 + cc + 1] = accv.y; \
            sLV[(r0 + i) * 33 + cc + 2] = accv.z; \
            sLV[(r0 + i) * 33 + cc + 3] = accv.w; \
            if (row < N) t += 4.f + (accv.x + accv.y + accv.z + accv.w) \
                - expf(accv.x) - expf(accv.y) - expf(accv.z) - expf(accv.w); }
        LV(0, acc0) LV(1, acc1) LV(2, acc2) LV(3, acc3)
        #undef LV
    }
    __syncthreads();
    if (c0 < 32) {
        #define ZROW(i, accv) { \
            int row = row0 + r0 + i; \
            if (row < N) { \
                float4 ep = *(const float4*)&eps[(size_t)row * 32 + c0]; \
                float l0 = sLV[(r0 + i) * 33 + c0 + 0]; \
                float l1 = sLV[(r0 + i) * 33 + c0 + 1]; \
                float l2 = sLV[(r0 + i) * 33 + c0 + 2]; \
                float l3 = sLV[(r0 + i) * 33 + c0 + 3]; \
                t -= accv.x * accv.x + accv.y * accv.y + accv.z * accv.z + accv.w * accv.w; \
                float z0 = accv.x + ep.x * expf(0.5f * l0); \
                float z1 = accv.y + ep.y * expf(0.5f * l1); \
                float z2 = accv.z + ep.z * expf(0.5f * l2); \
                float z3 = accv.w + ep.w * expf(0.5f * l3); \
                unsigned int pk = 0; \
                pk = __builtin_amdgcn_cvt_pk_fp8_f32(z0, z1, pk, false); \
                pk = __builtin_amdgcn_cvt_pk_fp8_f32(z2, z3, pk, true); \
                *(unsigned int*)&zb[(size_t)row * 32 + c0] = pk; } }
        ZROW(0, acc0) ZROW(1, acc1) ZROW(2, acc2) ZROW(3, acc3)
        #undef ZROW
    }
    #pragma unroll
    for (int m = 32; m; m >>= 1) t += __shfl_xor(t, m);
    __shared__ float red[4];
    if ((threadIdx.x & 63) == 0) red[threadIdx.x >> 6] = t;
    __syncthreads();
    if (threadIdx.x == 0) partial_kl[blockIdx.x] = red[0] + red[1] + red[2] + red[3];
}

// ---- decode + finalize -----------------------------------------------------

__device__ __forceinline__ void edge_idx(int e, int E, const int* __restrict__ pos,
        const int* __restrict__ neg, int& src, int& dst, float& label) {
    if (e < E) { src = NTL(pos[e]); dst = NTL(pos[E + e]); label = 1.f; }
    else       { src = NTL(neg[e - E]); dst = NTL(neg[e]); label = 0.f; }
}

__device__ __forceinline__ float bce_term(const unsigned char* __restrict__ zb,
        int src, int dst, float label) {
    const uint4* zs = (const uint4*)(zb + (size_t)src * 32);
    const uint4* zd = (const uint4*)(zb + (size_t)dst * 32);
    uint4 a0 = zs[0], a1 = zs[1];
    uint4 b0 = zd[0], b1 = zd[1];
    float p = dotfp8(a0.x, b0.x) + dotfp8(a0.y, b0.y)
            + dotfp8(a0.z, b0.z) + dotfp8(a0.w, b0.w)
            + dotfp8(a1.x, b1.x) + dotfp8(a1.y, b1.y)
            + dotfp8(a1.z, b1.z) + dotfp8(a1.w, b1.w);
    return fmaxf(p, 0.f) - p * label + log1pf(expf(-fabsf(p)));
}

// 2-edge ILP + index-prefetch software pipeline.
__global__ __launch_bounds__(256) void decode_kernel(const unsigned char* __restrict__ zb,
        const int* __restrict__ pos, const int* __restrict__ neg,
        float* __restrict__ partial_recon, int E) {
    int tid = blockIdx.x * blockDim.x + threadIdx.x;
    int stride = gridDim.x * blockDim.x;
    int total = 2 * E;
    float local = 0.f;
    int e = tid;
    int s1 = 0, d1 = 0, s2 = 0, d2 = 0;
    float l1 = 0.f, l2 = 0.f;
    bool h1 = e < total, h2 = (e + stride) < total;
    if (h1) edge_idx(e, E, pos, neg, s1, d1, l1);
    if (h2) edge_idx(e + stride, E, pos, neg, s2, d2, l2);
    while (h1) {
        int en = e + 2 * stride;
        int ns1 = 0, nd1 = 0, ns2 = 0, nd2 = 0;
        float nl1 = 0.f, nl2 = 0.f;
        bool nh1 = en < total, nh2 = (en + stride) < total;
        if (nh1) edge_idx(en, E, pos, neg, ns1, nd1, nl1);
        if (nh2) edge_idx(en + stride, E, pos, neg, ns2, nd2, nl2);
        local += bce_term(zb, s1, d1, l1);
        if (h2) local += bce_term(zb, s2, d2, l2);
        s1 = ns1; d1 = nd1; l1 = nl1;
        s2 = ns2; d2 = nd2; l2 = nl2;
        h1 = nh1; h2 = nh2; e = en;
    }
    #pragma unroll
    for (int m = 32; m; m >>= 1) local += __shfl_xor(local, m);
    __shared__ float red[4];
    if ((threadIdx.x & 63) == 0) red[threadIdx.x >> 6] = local;
    __syncthreads();
    if (threadIdx.x == 0) partial_recon[blockIdx.x] = red[0] + red[1] + red[2] + red[3];
}

__global__ __launch_bounds__(256) void finalize_kernel(const float* __restrict__ partial_recon,
        const float* __restrict__ partial_kl, float* __restrict__ out,
        int nkl, int E, int N) {
    float r = 0.f, k = 0.f;
    for (int i = threadIdx.x; i < NRED; i += 256) r += partial_recon[i];
    for (int i = threadIdx.x; i < nkl; i += 256) k += partial_kl[i];
    #pragma unroll
    for (int m = 32; m; m >>= 1) { r += __shfl_xor(r, m); k += __shfl_xor(k, m); }
    __shared__ float redr[4], redk[4];
    if ((threadIdx.x & 63) == 0) { redr[threadIdx.x >> 6] = r; redk[threadIdx.x >> 6] = k; }
    __syncthreads();
    if (threadIdx.x == 0) {
        float recon = (redr[0] + redr[1] + redr[2] + redr[3]) / (float)(2 * E);
        float kl = -0.5f * (redk[0] + redk[1] + redk[2] + redk[3]) / ((float)N * 32.f);
        out[0] = recon + kl;
        out[1] = recon;
        out[2] = kl;
    }
}

extern "C" void kernel_launch(void* const* d_in, const int* in_sizes, int n_in,
                              void* d_out, int out_size, void* d_ws, size_t ws_size,
                              hipStream_t stream) {
    const float* x   = (const float*)d_in[0];
    const float* eps = (const float*)d_in[1];
    const float* W1  = (const float*)d_in[2];
    const float* b1  = (const float*)d_in[3];
    const float* Wmu = (const float*)d_in[4];
    const float* bmu = (const float*)d_in[5];
    const float* Wlv = (const float*)d_in[6];
    const float* blv = (const float*)d_in[7];
    const int* ei  = (const int*)d_in[8];
    const int* nei = (const int*)d_in[9];
    float* out = (float*)d_out;

    const int N = in_sizes[0] / 128;   // 100000
    const int E = in_sizes[8] / 2;     // 1600000
    const int nbuck = (N + NPB - 1) / NPB;   // 782 (<=1024 required by scan)

    // Workspace layout (t1_8 dead after aggregate_q88; zb aliases it):
    char* ws = (char*)d_ws;
    size_t off = 0;
    unsigned int* t1_8 = (unsigned int*)(ws + off); off += (size_t)N * 64;   // (x@W1)*dinv (fp8)
    unsigned char* zb8 = (unsigned char*)t1_8;                                // z (fp8), aliased
    unsigned int* hb8  = (unsigned int*)(ws + off); off += (size_t)N * 64;   // h*dinv (fp8)
    float* g    = (float*)(ws + off); off += (size_t)N * 64 * 4;             // Ahat h (f32)
    int* pairs  = (int*)(ws + off);   off += (size_t)E * 4;                  // packed (src,dstlocal)
    int* col    = (int*)(ws + off);   off += (size_t)E * 4;
    int* deg    = (int*)(ws + off);   off += (size_t)N * 4;
    int* row_start = (int*)(ws + off); off += (size_t)N * 4;
    float* dinv = (float*)(ws + off); off += (size_t)N * 4;
    int* bcnt   = (int*)(ws + off);   off += (size_t)(nbuck + 1) * 4;
    int* boff   = (int*)(ws + off);   off += (size_t)(nbuck + 1) * 4;
    int* bcur   = (int*)(ws + off);   off += (size_t)(nbuck + 1) * 4;
    float* partial_recon = (float*)(ws + off); off += NRED * 4;
    float* partial_kl    = (float*)(ws + off); off += 4096 * 4;

    hipMemsetAsync(bcnt, 0, (size_t)nbuck * 4, stream);

    // CSR build (also produces dinv, needed by gemm_k128's pre-scale)
    bucket_hist<<<256, 256, nbuck * 4, stream>>>(ei + E, bcnt, E, nbuck);
    bucket_scan<<<1, 1024, 0, stream>>>(bcnt, boff, bcur, E, nbuck);
    int nsc = (E + SCH - 1) / SCH;
    bucket_scatter<<<nsc, 256, 2 * nbuck * 4, stream>>>(ei, bcur, pairs, E, nbuck);
    bucket_finalize<<<nbuck, 256, 0, stream>>>(pairs, boff, row_start, deg, dinv, col, N, nbuck);

    gemm_k128<<<(N + 63) / 64, 256, 0, stream>>>(x, W1, dinv, t1_8, N);

    int qb = (N * 16 + 255) / 256;   // quarter-wave per node
    aggregate_q88<<<qb, 256, 0, stream>>>(t1_8, hb8, row_start, deg, col, dinv, b1, N);
    aggregate_q8f<<<qb, 256, 0, stream>>>(hb8, g, row_start, deg, col, dinv, N);

    int ncat = (N + 63) / 64;
    gemm_cat_fused<<<ncat, 256, 0, stream>>>(g, Wmu, Wlv, bmu, blv, eps, zb8, partial_kl, N);

    decode_kernel<<<NRED, 256, 0, stream>>>(zb8, ei, nei, partial_recon, E);
    finalize_kernel<<<1, 256, 0, stream>>>(partial_recon, partial_kl, out, ncat, E, N);
}

// Round 15
// 242.677 us; speedup vs baseline: 1.0441x; 1.0441x over previous
//
#include <hip/hip_runtime.h>
#include <math.h>

// ---------------------------------------------------------------------------
// GraphVAE forward. History:
// R1: atomic-convoy -> grid-stride partials. R2: decode thread-per-edge.
// R3: bf16 + unroll + fused z/KL. R4: bucketed CSR build.
// R5: z -> fp8 (L2-resident). R6: tables -> fp8 (FETCH halved, dur flat).
// R7: pre-scaled rows + quarter-wave => 242us.
// R8-R11: planar-split FAILED. R12: linearity fusion FAILED (gather
//     LATENCY, not stream bytes, is the cost). R13: revert+decode pipeline
//     => 248; exposed gemm_k128 (17% occ, 65KB LDS) + bucket_scatter.
// R14: gemm K-chunk WORKED (out of top-5). Scatter SCH 16384 BACKFIRED
//     (58us @ 3.5% occupancy): reservation scheme trades grid size vs
//     atomic contention - both ends measured bad.
// R15: atomic-free 3-pass counting sort: per-chunk histogram matrix ->
//     per-bucket column scan (782 parallel serial-scan lanes, unroll-16)
//     -> cursor-row scatter with zero global atomics at any grid size.
// ---------------------------------------------------------------------------

#define NRED 2048        // partial-reduction blocks for decode
#define NPB 128          // nodes per bucket (power of 2)
#define NPB_SHIFT 7
#define SCH 2048         // edges per histogram/scatter chunk

typedef float f32x2 __attribute__((ext_vector_type(2)));

#define NTL(p) __builtin_nontemporal_load(&(p))

// dot of 4 fp8 pairs packed in two uints (HW fp8->f32 converts)
__device__ __forceinline__ float dotfp8(unsigned int a, unsigned int b) {
    f32x2 al = __builtin_amdgcn_cvt_pk_f32_fp8(a, false);
    f32x2 ah = __builtin_amdgcn_cvt_pk_f32_fp8(a, true);
    f32x2 bl = __builtin_amdgcn_cvt_pk_f32_fp8(b, false);
    f32x2 bh = __builtin_amdgcn_cvt_pk_f32_fp8(b, true);
    return al.x * bl.x + al.y * bl.y + ah.x * bh.x + ah.y * bh.y;
}

// ---- atomic-free bucketed CSR build ----------------------------------------

// Pass 1: per-chunk private bucket histogram -> hist_mx[blk][nbuck].
__global__ __launch_bounds__(256) void hist2(const int* __restrict__ dst,
        int* __restrict__ hist_mx, int E, int nbuck) {
    extern __shared__ int sh[];
    int blk = blockIdx.x;
    int e0 = blk * SCH, e1 = min(e0 + SCH, E);
    for (int i = threadIdx.x; i < nbuck; i += 256) sh[i] = 0;
    __syncthreads();
    for (int e = e0 + threadIdx.x; e < e1; e += 256)
        atomicAdd(&sh[dst[e] >> NPB_SHIFT], 1);
    __syncthreads();
    int* row = hist_mx + (size_t)blk * nbuck;
    for (int i = threadIdx.x; i < nbuck; i += 256) row[i] = sh[i];
}

// Pass 2a: one thread per bucket scans its column (over chunks) in place:
// hist_mx[j][b] <- exclusive prefix; bcnt[b] <- total. Unroll-16 for MLP.
__global__ __launch_bounds__(256) void colscan(int* __restrict__ hist_mx,
        int* __restrict__ bcnt, int B, int nbuck) {
    int b = blockIdx.x * 256 + threadIdx.x;
    if (b >= nbuck) return;
    int carry = 0;
    int j = 0;
    for (; j + 16 <= B; j += 16) {
        int v[16];
        #pragma unroll
        for (int u = 0; u < 16; ++u) v[u] = hist_mx[(size_t)(j + u) * nbuck + b];
        int run = carry;
        #pragma unroll
        for (int u = 0; u < 16; ++u) {
            hist_mx[(size_t)(j + u) * nbuck + b] = run;
            run += v[u];
        }
        carry = run;
    }
    for (; j < B; ++j) {
        int v = hist_mx[(size_t)j * nbuck + b];
        hist_mx[(size_t)j * nbuck + b] = carry;
        carry += v;
    }
    bcnt[b] = carry;
}

// Pass 2b: exclusive scan of bucket totals -> boff (nbuck <= 1024).
__global__ __launch_bounds__(1024) void bucket_scan(const int* __restrict__ bcnt,
        int* __restrict__ boff, int E, int nbuck) {
    __shared__ int s[1024];
    int tid = threadIdx.x;
    int v = (tid < nbuck) ? bcnt[tid] : 0;
    s[tid] = v;
    __syncthreads();
    for (int off = 1; off < 1024; off <<= 1) {
        int t = (tid >= off) ? s[tid - off] : 0;
        __syncthreads();
        if (tid >= off) s[tid] += t;
        __syncthreads();
    }
    if (tid < nbuck) boff[tid] = s[tid] - v;
    if (tid == 0) boff[nbuck] = E;
}

// Pass 3: scatter with precomputed per-(chunk,bucket) cursors. No global
// atomics; each chunk's range within each bucket is disjoint by construction.
__global__ __launch_bounds__(256) void scatter2(const int* __restrict__ ei,
        const int* __restrict__ hist_mx, const int* __restrict__ boff,
        int* __restrict__ pairs, int E, int nbuck) {
    extern __shared__ int sh[];
    int blk = blockIdx.x;
    int e0 = blk * SCH, e1 = min(e0 + SCH, E);
    const int* row = hist_mx + (size_t)blk * nbuck;
    for (int i = threadIdx.x; i < nbuck; i += 256) sh[i] = boff[i] + row[i];
    __syncthreads();
    for (int e = e0 + threadIdx.x; e < e1; e += 256) {
        int s = ei[e], t = ei[E + e];
        int b = t >> NPB_SHIFT;
        int slot = atomicAdd(&sh[b], 1);
        pairs[slot] = (s << NPB_SHIFT) | (t & (NPB - 1));
    }
}

__global__ __launch_bounds__(256) void bucket_finalize(const int* __restrict__ pairs,
        const int* __restrict__ boff, int* __restrict__ row_start,
        int* __restrict__ deg, float* __restrict__ dinv, int* __restrict__ col,
        int N, int nbuck) {
    __shared__ int cnt[NPB], start[NPB], cur[NPB];
    int b = blockIdx.x;
    int node0 = b << NPB_SHIFT;
    int p0 = boff[b], p1 = boff[b + 1];
    if (threadIdx.x < NPB) cnt[threadIdx.x] = 0;
    __syncthreads();
    for (int p = p0 + threadIdx.x; p < p1; p += 256)
        atomicAdd(&cnt[pairs[p] & (NPB - 1)], 1);
    __syncthreads();
    if (threadIdx.x == 0) {
        int acc = 0;
        for (int i = 0; i < NPB; ++i) { start[i] = acc; acc += cnt[i]; }
    }
    __syncthreads();
    if (threadIdx.x < NPB) {
        int node = node0 + threadIdx.x;
        if (node < N) {
            int d = cnt[threadIdx.x];
            deg[node] = d;
            row_start[node] = p0 + start[threadIdx.x];
            dinv[node] = rsqrtf((float)(d + 1));
        }
        cur[threadIdx.x] = 0;
    }
    __syncthreads();
    for (int p = p0 + threadIdx.x; p < p1; p += 256) {
        int pr = pairs[p];
        int l = pr & (NPB - 1);
        int slot = p0 + start[l] + atomicAdd(&cur[l], 1);
        col[slot] = pr >> NPB_SHIFT;
    }
}

// ---- dense layers ----------------------------------------------------------

// C[N,64](fp8) = (A[N,128] @ W[128,64]) * dinv[row]; K chunked 4x32 (17.4KB LDS).
__global__ __launch_bounds__(256) void gemm_k128(const float* __restrict__ A,
        const float* __restrict__ W, const float* __restrict__ dinv,
        unsigned int* __restrict__ Cb32, int N) {
    const int K = 128, KC = 32;
    __shared__ float sA[64][KC + 4];
    __shared__ float sW[KC][64];
    int row0 = blockIdx.x * 64;
    int tid = threadIdx.x;
    int ty = tid >> 4, tx = tid & 15;
    int r0 = ty * 4, c0 = tx * 4;
    float4 acc0 = make_float4(0,0,0,0), acc1 = acc0, acc2 = acc0, acc3 = acc0;
    for (int kc = 0; kc < K; kc += KC) {
        __syncthreads();
        for (int i = tid; i < KC * 64 / 4; i += 256)
            ((float4*)sW)[i] = ((const float4*)(W + (size_t)kc * 64))[i];
        for (int i = tid; i < 64 * KC / 4; i += 256) {
            int r = (i * 4) / KC, c = (i * 4) % KC;
            float4 v = make_float4(0.f, 0.f, 0.f, 0.f);
            if (row0 + r < N) v = *(const float4*)&A[(size_t)(row0 + r) * K + kc + c];
            *(float4*)&sA[r][c] = v;
        }
        __syncthreads();
        for (int k = 0; k < KC; ++k) {
            float4 wv = *(float4*)&sW[k][c0];
            float a0 = sA[r0 + 0][k];
            float a1 = sA[r0 + 1][k];
            float a2 = sA[r0 + 2][k];
            float a3 = sA[r0 + 3][k];
            acc0.x += a0 * wv.x; acc0.y += a0 * wv.y; acc0.z += a0 * wv.z; acc0.w += a0 * wv.w;
            acc1.x += a1 * wv.x; acc1.y += a1 * wv.y; acc1.z += a1 * wv.z; acc1.w += a1 * wv.w;
            acc2.x += a2 * wv.x; acc2.y += a2 * wv.y; acc2.z += a2 * wv.z; acc2.w += a2 * wv.w;
            acc3.x += a3 * wv.x; acc3.y += a3 * wv.y; acc3.z += a3 * wv.z; acc3.w += a3 * wv.w;
        }
    }
    #define ST_F8(i, accv) \
        if (row0 + r0 + i < N) { \
            float di = dinv[row0 + r0 + i]; \
            unsigned int pk = 0; \
            pk = __builtin_amdgcn_cvt_pk_fp8_f32(accv.x * di, accv.y * di, pk, false); \
            pk = __builtin_amdgcn_cvt_pk_fp8_f32(accv.z * di, accv.w * di, pk, true); \
            Cb32[((row0 + r0 + i) << 4) + (c0 >> 2)] = pk; }
    ST_F8(0, acc0) ST_F8(1, acc1) ST_F8(2, acc2) ST_F8(3, acc3)
    #undef ST_F8
}

// ---- aggregations (pull over CSR, pre-scaled fp8 tables) --------------------

#define ACC4(gg, P) { \
    f32x2 L_ = __builtin_amdgcn_cvt_pk_f32_fp8(gg, false); \
    f32x2 H_ = __builtin_amdgcn_cvt_pk_f32_fp8(gg, true); \
    P##0 += L_.x; P##1 += L_.y; P##2 += H_.x; P##3 += H_.y; }

#define AGG_SUM(tab) \
    float a0, a1, a2, a3, b0 = 0.f, b1 = 0.f, b2 = 0.f, b3 = 0.f; \
    { unsigned int v = tab[(q << 4) | l]; \
      f32x2 L_ = __builtin_amdgcn_cvt_pk_f32_fp8(v, false); \
      f32x2 H_ = __builtin_amdgcn_cvt_pk_f32_fp8(v, true); \
      a0 = L_.x; a1 = L_.y; a2 = H_.x; a3 = H_.y; } \
    { int base = row_start[q], d = deg[q]; \
      int j = 0; \
      for (; j + 8 <= d; j += 8) { \
        int s0 = col[base + j + 0], s1 = col[base + j + 1]; \
        int s2 = col[base + j + 2], s3 = col[base + j + 3]; \
        int s4 = col[base + j + 4], s5 = col[base + j + 5]; \
        int s6 = col[base + j + 6], s7 = col[base + j + 7]; \
        unsigned int g0 = tab[(s0 << 4) | l], g1 = tab[(s1 << 4) | l]; \
        unsigned int g2 = tab[(s2 << 4) | l], g3 = tab[(s3 << 4) | l]; \
        unsigned int g4 = tab[(s4 << 4) | l], g5 = tab[(s5 << 4) | l]; \
        unsigned int g6 = tab[(s6 << 4) | l], g7 = tab[(s7 << 4) | l]; \
        ACC4(g0, a) ACC4(g1, b) ACC4(g2, a) ACC4(g3, b) \
        ACC4(g4, a) ACC4(g5, b) ACC4(g6, a) ACC4(g7, b) \
      } \
      for (; j < d; ++j) { \
        int s = col[base + j]; \
        unsigned int g = tab[(s << 4) | l]; \
        ACC4(g, a) \
      } }

// fp8 in -> fp8 out: h = relu(di*sum + b); stored h*di (pre-scaled for next).
__global__ __launch_bounds__(256) void aggregate_q88(const unsigned int* __restrict__ hs,
        unsigned int* __restrict__ hout, const int* __restrict__ row_start,
        const int* __restrict__ deg, const int* __restrict__ col,
        const float* __restrict__ dinv, const float* __restrict__ bias, int N) {
    int q = (blockIdx.x * blockDim.x + threadIdx.x) >> 4;
    int l = threadIdx.x & 15;
    if (q >= N) return;
    float di = dinv[q];
    AGG_SUM(hs)
    float4 bv = *(const float4*)&bias[l << 2];
    float r0 = fmaxf(di * (a0 + b0) + bv.x, 0.f) * di;
    float r1 = fmaxf(di * (a1 + b1) + bv.y, 0.f) * di;
    float r2 = fmaxf(di * (a2 + b2) + bv.z, 0.f) * di;
    float r3 = fmaxf(di * (a3 + b3) + bv.w, 0.f) * di;
    unsigned int pk = 0;
    pk = __builtin_amdgcn_cvt_pk_fp8_f32(r0, r1, pk, false);
    pk = __builtin_amdgcn_cvt_pk_fp8_f32(r2, r3, pk, true);
    hout[(q << 4) | l] = pk;
}

// fp8 in -> f32 out (g = Ahat h), no bias/relu, no output pre-scale.
__global__ __launch_bounds__(256) void aggregate_q8f(const unsigned int* __restrict__ hs,
        float* __restrict__ gout, const int* __restrict__ row_start,
        const int* __restrict__ deg, const int* __restrict__ col,
        const float* __restrict__ dinv, int N) {
    int q = (blockIdx.x * blockDim.x + threadIdx.x) >> 4;
    int l = threadIdx.x & 15;
    if (q >= N) return;
    float di = dinv[q];
    AGG_SUM(hs)
    float4 r;
    r.x = di * (a0 + b0); r.y = di * (a1 + b1);
    r.z = di * (a2 + b2); r.w = di * (a3 + b3);
    *(float4*)&gout[(q << 6) | (l << 2)] = r;
}

// ---- mu/lv GEMM with fused z (fp8) + KL ------------------------------------

__global__ __launch_bounds__(256) void gemm_cat_fused(const float* __restrict__ A,
        const float* __restrict__ Wmu, const float* __restrict__ Wlv,
        const float* __restrict__ bmu, const float* __restrict__ blv,
        const float* __restrict__ eps, unsigned char* __restrict__ zb,
        float* __restrict__ partial_kl, int N) {
    const int K = 64;
    __shared__ float sA[64 * (K + 4)];
    __shared__ float sW[K * 64];
    __shared__ float sB[64];
    int row0 = blockIdx.x * 64;
    int tid = threadIdx.x;
    for (int i = tid; i < K * 64 / 4; i += 256) {
        int k = (i * 4) / 64, c = (i * 4) % 64;
        float4 v;
        if (c < 32) v = *(const float4*)&Wmu[k * 32 + c];
        else        v = *(const float4*)&Wlv[k * 32 + (c - 32)];
        *(float4*)&sW[k * 64 + c] = v;
    }
    if (tid < 32) sB[tid] = bmu[tid];
    else if (tid < 64) sB[tid] = blv[tid - 32];
    for (int i = tid; i < 64 * K / 4; i += 256) {
        int r = (i * 4) / K, c = (i * 4) % K;
        float4 v = make_float4(0.f, 0.f, 0.f, 0.f);
        if (row0 + r < N) v = *(const float4*)&A[(size_t)(row0 + r) * K + c];
        *(float4*)&sA[r * (K + 4) + c] = v;
    }
    __syncthreads();
    int ty = tid >> 4, tx = tid & 15;
    int r0 = ty * 4, c0 = tx * 4;
    float4 acc0 = make_float4(0,0,0,0), acc1 = acc0, acc2 = acc0, acc3 = acc0;
    for (int k = 0; k < K; ++k) {
        float4 wv = *(float4*)&sW[k * 64 + c0];
        float a0 = sA[(r0 + 0) * (K + 4) + k];
        float a1 = sA[(r0 + 1) * (K + 4) + k];
        float a2 = sA[(r0 + 2) * (K + 4) + k];
        float a3 = sA[(r0 + 3) * (K + 4) + k];
        acc0.x += a0 * wv.x; acc0.y += a0 * wv.y; acc0.z += a0 * wv.z; acc0.w += a0 * wv.w;
        acc1.x += a1 * wv.x; acc1.y += a1 * wv.y; acc1.z += a1 * wv.z; acc1.w += a1 * wv.w;
        acc2.x += a2 * wv.x; acc2.y += a2 * wv.y; acc2.z += a2 * wv.z; acc2.w += a2 * wv.w;
        acc3.x += a3 * wv.x; acc3.y += a3 * wv.y; acc3.z += a3 * wv.z; acc3.w += a3 * wv.w;
    }
    float4 bv = *(float4*)&sB[c0];
    acc0.x += bv.x; acc0.y += bv.y; acc0.z += bv.z; acc0.w += bv.w;
    acc1.x += bv.x; acc1.y += bv.y; acc1.z += bv.z; acc1.w += bv.w;
    acc2.x += bv.x; acc2.y += bv.y; acc2.z += bv.z; acc2.w += bv.w;
    acc3.x += bv.x; acc3.y += bv.y; acc3.z += bv.z; acc3.w += bv.w;

    float* sLV = sA;                 // aliased; sA dead after sync
    __syncthreads();
    float t = 0.f;
    if (c0 >= 32) {
        int cc = c0 - 32;
        #define LV(i, accv) { \
            int row = row0 + r0 + i; \
            sLV[(r0 + i) * 33 + cc + 0] = accv.x; \
            sLV[(r0 + i) * 33 + cc + 1] = accv.y; \
            sLV[(r0 + i) * 33 + cc + 2] = accv.z; \
            sLV[(r0 + i) * 33 + cc + 3] = accv.w; \
            if (row < N) t += 4.f + (accv.x + accv.y + accv.z + accv.w) \
                - expf(accv.x) - expf(accv.y) - expf(accv.z) - expf(accv.w); }
        LV(0, acc0) LV(1, acc1) LV(2, acc2) LV(3, acc3)
        #undef LV
    }
    __syncthreads();
    if (c0 < 32) {
        #define ZROW(i, accv) { \
            int row = row0 + r0 + i; \
            if (row < N) { \
                float4 ep = *(const float4*)&eps[(size_t)row * 32 + c0]; \
                float l0 = sLV[(r0 + i) * 33 + c0 + 0]; \
                float l1 = sLV[(r0 + i) * 33 + c0 + 1]; \
                float l2 = sLV[(r0 + i) * 33 + c0 + 2]; \
                float l3 = sLV[(r0 + i) * 33 + c0 + 3]; \
                t -= accv.x * accv.x + accv.y * accv.y + accv.z * accv.z + accv.w * accv.w; \
                float z0 = accv.x + ep.x * expf(0.5f * l0); \
                float z1 = accv.y + ep.y * expf(0.5f * l1); \
                float z2 = accv.z + ep.z * expf(0.5f * l2); \
                float z3 = accv.w + ep.w * expf(0.5f * l3); \
                unsigned int pk = 0; \
                pk = __builtin_amdgcn_cvt_pk_fp8_f32(z0, z1, pk, false); \
                pk = __builtin_amdgcn_cvt_pk_fp8_f32(z2, z3, pk, true); \
                *(unsigned int*)&zb[(size_t)row * 32 + c0] = pk; } }
        ZROW(0, acc0) ZROW(1, acc1) ZROW(2, acc2) ZROW(3, acc3)
        #undef ZROW
    }
    #pragma unroll
    for (int m = 32; m; m >>= 1) t += __shfl_xor(t, m);
    __shared__ float red[4];
    if ((threadIdx.x & 63) == 0) red[threadIdx.x >> 6] = t;
    __syncthreads();
    if (threadIdx.x == 0) partial_kl[blockIdx.x] = red[0] + red[1] + red[2] + red[3];
}

// ---- decode + finalize -----------------------------------------------------

__device__ __forceinline__ void edge_idx(int e, int E, const int* __restrict__ pos,
        const int* __restrict__ neg, int& src, int& dst, float& label) {
    if (e < E) { src = NTL(pos[e]); dst = NTL(pos[E + e]); label = 1.f; }
    else       { src = NTL(neg[e - E]); dst = NTL(neg[e]); label = 0.f; }
}

__device__ __forceinline__ float bce_term(const unsigned char* __restrict__ zb,
        int src, int dst, float label) {
    const uint4* zs = (const uint4*)(zb + (size_t)src * 32);
    const uint4* zd = (const uint4*)(zb + (size_t)dst * 32);
    uint4 a0 = zs[0], a1 = zs[1];
    uint4 b0 = zd[0], b1 = zd[1];
    float p = dotfp8(a0.x, b0.x) + dotfp8(a0.y, b0.y)
            + dotfp8(a0.z, b0.z) + dotfp8(a0.w, b0.w)
            + dotfp8(a1.x, b1.x) + dotfp8(a1.y, b1.y)
            + dotfp8(a1.z, b1.z) + dotfp8(a1.w, b1.w);
    return fmaxf(p, 0.f) - p * label + log1pf(expf(-fabsf(p)));
}

// 2-edge ILP + index-prefetch software pipeline.
__global__ __launch_bounds__(256) void decode_kernel(const unsigned char* __restrict__ zb,
        const int* __restrict__ pos, const int* __restrict__ neg,
        float* __restrict__ partial_recon, int E) {
    int tid = blockIdx.x * blockDim.x + threadIdx.x;
    int stride = gridDim.x * blockDim.x;
    int total = 2 * E;
    float local = 0.f;
    int e = tid;
    int s1 = 0, d1 = 0, s2 = 0, d2 = 0;
    float l1 = 0.f, l2 = 0.f;
    bool h1 = e < total, h2 = (e + stride) < total;
    if (h1) edge_idx(e, E, pos, neg, s1, d1, l1);
    if (h2) edge_idx(e + stride, E, pos, neg, s2, d2, l2);
    while (h1) {
        int en = e + 2 * stride;
        int ns1 = 0, nd1 = 0, ns2 = 0, nd2 = 0;
        float nl1 = 0.f, nl2 = 0.f;
        bool nh1 = en < total, nh2 = (en + stride) < total;
        if (nh1) edge_idx(en, E, pos, neg, ns1, nd1, nl1);
        if (nh2) edge_idx(en + stride, E, pos, neg, ns2, nd2, nl2);
        local += bce_term(zb, s1, d1, l1);
        if (h2) local += bce_term(zb, s2, d2, l2);
        s1 = ns1; d1 = nd1; l1 = nl1;
        s2 = ns2; d2 = nd2; l2 = nl2;
        h1 = nh1; h2 = nh2; e = en;
    }
    #pragma unroll
    for (int m = 32; m; m >>= 1) local += __shfl_xor(local, m);
    __shared__ float red[4];
    if ((threadIdx.x & 63) == 0) red[threadIdx.x >> 6] = local;
    __syncthreads();
    if (threadIdx.x == 0) partial_recon[blockIdx.x] = red[0] + red[1] + red[2] + red[3];
}

__global__ __launch_bounds__(256) void finalize_kernel(const float* __restrict__ partial_recon,
        const float* __restrict__ partial_kl, float* __restrict__ out,
        int nkl, int E, int N) {
    float r = 0.f, k = 0.f;
    for (int i = threadIdx.x; i < NRED; i += 256) r += partial_recon[i];
    for (int i = threadIdx.x; i < nkl; i += 256) k += partial_kl[i];
    #pragma unroll
    for (int m = 32; m; m >>= 1) { r += __shfl_xor(r, m); k += __shfl_xor(k, m); }
    __shared__ float redr[4], redk[4];
    if ((threadIdx.x & 63) == 0) { redr[threadIdx.x >> 6] = r; redk[threadIdx.x >> 6] = k; }
    __syncthreads();
    if (threadIdx.x == 0) {
        float recon = (redr[0] + redr[1] + redr[2] + redr[3]) / (float)(2 * E);
        float kl = -0.5f * (redk[0] + redk[1] + redk[2] + redk[3]) / ((float)N * 32.f);
        out[0] = recon + kl;
        out[1] = recon;
        out[2] = kl;
    }
}

extern "C" void kernel_launch(void* const* d_in, const int* in_sizes, int n_in,
                              void* d_out, int out_size, void* d_ws, size_t ws_size,
                              hipStream_t stream) {
    const float* x   = (const float*)d_in[0];
    const float* eps = (const float*)d_in[1];
    const float* W1  = (const float*)d_in[2];
    const float* b1  = (const float*)d_in[3];
    const float* Wmu = (const float*)d_in[4];
    const float* bmu = (const float*)d_in[5];
    const float* Wlv = (const float*)d_in[6];
    const float* blv = (const float*)d_in[7];
    const int* ei  = (const int*)d_in[8];
    const int* nei = (const int*)d_in[9];
    float* out = (float*)d_out;

    const int N = in_sizes[0] / 128;   // 100000
    const int E = in_sizes[8] / 2;     // 1600000
    const int nbuck = (N + NPB - 1) / NPB;   // 782 (<=1024 required by scan)
    const int B = (E + SCH - 1) / SCH;       // 782 chunks

    // Workspace layout (t1_8 dead after aggregate_q88; zb aliases it):
    char* ws = (char*)d_ws;
    size_t off = 0;
    unsigned int* t1_8 = (unsigned int*)(ws + off); off += (size_t)N * 64;   // (x@W1)*dinv (fp8)
    unsigned char* zb8 = (unsigned char*)t1_8;                                // z (fp8), aliased
    unsigned int* hb8  = (unsigned int*)(ws + off); off += (size_t)N * 64;   // h*dinv (fp8)
    float* g    = (float*)(ws + off); off += (size_t)N * 64 * 4;             // Ahat h (f32)
    int* pairs  = (int*)(ws + off);   off += (size_t)E * 4;                  // packed (src,dstlocal)
    int* col    = (int*)(ws + off);   off += (size_t)E * 4;
    int* deg    = (int*)(ws + off);   off += (size_t)N * 4;
    int* row_start = (int*)(ws + off); off += (size_t)N * 4;
    float* dinv = (float*)(ws + off); off += (size_t)N * 4;
    int* hist_mx = (int*)(ws + off);  off += (size_t)B * nbuck * 4;          // 2.45MB
    int* bcnt   = (int*)(ws + off);   off += (size_t)(nbuck + 1) * 4;
    int* boff   = (int*)(ws + off);   off += (size_t)(nbuck + 1) * 4;
    float* partial_recon = (float*)(ws + off); off += NRED * 4;
    float* partial_kl    = (float*)(ws + off); off += 4096 * 4;

    // CSR build (atomic-free counting sort; also produces dinv via finalize)
    hist2<<<B, 256, nbuck * 4, stream>>>(ei + E, hist_mx, E, nbuck);
    colscan<<<(nbuck + 255) / 256, 256, 0, stream>>>(hist_mx, bcnt, B, nbuck);
    bucket_scan<<<1, 1024, 0, stream>>>(bcnt, boff, E, nbuck);
    scatter2<<<B, 256, nbuck * 4, stream>>>(ei, hist_mx, boff, pairs, E, nbuck);
    bucket_finalize<<<nbuck, 256, 0, stream>>>(pairs, boff, row_start, deg, dinv, col, N, nbuck);

    gemm_k128<<<(N + 63) / 64, 256, 0, stream>>>(x, W1, dinv, t1_8, N);

    int qb = (N * 16 + 255) / 256;   // quarter-wave per node
    aggregate_q88<<<qb, 256, 0, stream>>>(t1_8, hb8, row_start, deg, col, dinv, b1, N);
    aggregate_q8f<<<qb, 256, 0, stream>>>(hb8, g, row_start, deg, col, dinv, N);

    int ncat = (N + 63) / 64;
    gemm_cat_fused<<<ncat, 256, 0, stream>>>(g, Wmu, Wlv, bmu, blv, eps, zb8, partial_kl, N);

    decode_kernel<<<NRED, 256, 0, stream>>>(zb8, ei, nei, partial_recon, E);
    finalize_kernel<<<1, 256, 0, stream>>>(partial_recon, partial_kl, out, ncat, E, N);
}